// Round 1
// baseline (6792.251 us; speedup 1.0000x reference)
//
#include <hip/hip_runtime.h>
#include <hip/hip_bf16.h>
#include <math.h>

#define B_ 32
#define T_ 128
#define V_ 32000
#define D_ 512
#define H_ 512

typedef __attribute__((ext_vector_type(8))) short bf16x8;
typedef __attribute__((ext_vector_type(4))) float f32x4;

#define AS1 __attribute__((address_space(1)))
#define AS3 __attribute__((address_space(3)))

__device__ __forceinline__ unsigned short f2bf(float x) {
  unsigned int b = __float_as_uint(x);
  return (unsigned short)((b + 0x7FFFu + ((b >> 16) & 1u)) >> 16);
}

__device__ __forceinline__ float sigm(float x) { return 1.0f / (1.0f + expf(-x)); }

// ---------------- embedding gather: emb[t*32+b][:] = E[dst[b][t]][:]
__global__ __launch_bounds__(64) void embed_kernel(const int* __restrict__ dst,
                                                   const float* __restrict__ E,
                                                   float* __restrict__ emb) {
  int rt = blockIdx.x;           // t*32 + b
  int t = rt >> 5, b = rt & 31;
  int v = dst[b * T_ + t];
  const float4* src = (const float4*)(E + (size_t)v * D_);
  float4* d = (float4*)(emb + (size_t)rt * D_);
  d[threadIdx.x] = src[threadIdx.x];
  d[threadIdx.x + 64] = src[threadIdx.x + 64];
}

// ---------------- f32 -> bf16 (RNE), 4 at a time
__global__ void cvt_kernel(const float* __restrict__ in, unsigned short* __restrict__ out, int n4) {
  int stride = gridDim.x * blockDim.x;
  for (int i = blockIdx.x * blockDim.x + threadIdx.x; i < n4; i += stride) {
    float4 v = ((const float4*)in)[i];
    ushort4 o;
    o.x = f2bf(v.x); o.y = f2bf(v.y); o.z = f2bf(v.z); o.w = f2bf(v.w);
    ((ushort4*)out)[i] = o;
  }
}

// ---------------- one LSTM step
// grid (16 k-tiles, 4 b-tiles), 256 threads.
// threads: row = tid&127 -> (gate = row>>5, klocal = row&31); half = tid>>7 picks 4 of 8 batches.
__global__ __launch_bounds__(256) void lstm_step_kernel(
    int t,
    const float* __restrict__ emb,       // [T*B][512]
    const float* __restrict__ Wih,       // [2048][1024]
    const float* __restrict__ Whh,       // [2048][512]
    const float* __restrict__ bih,
    const float* __restrict__ bhh,
    const float* __restrict__ hprev, int hstride,
    const float* __restrict__ oprev, int ostride,
    const float* __restrict__ cprev,     // [B][512]
    float* __restrict__ cnew,            // [B][512]
    float* __restrict__ hout, int hostride) // base = outs + t*512, stride = T*512
{
  __shared__ float xs[8][1536];          // [emb(512) | out_prev(512) | h_prev(512)]
  __shared__ float gl[4][32][8];
  const int tid = threadIdx.x;
  const int kt = blockIdx.x;
  const int b0 = blockIdx.y * 8;

  {
    const float* ebase = emb + ((size_t)t * B_ + b0) * D_;
    for (int idx = tid; idx < 3072; idx += 256) {   // 8 rows * 384 float4
      int b = idx / 384;
      int c4 = idx - b * 384;
      int c = c4 * 4;
      float4 v;
      if (c < 512)       v = *(const float4*)(ebase + (size_t)b * D_ + c);
      else if (c < 1024) v = *(const float4*)(oprev + (size_t)(b0 + b) * ostride + (c - 512));
      else               v = *(const float4*)(hprev + (size_t)(b0 + b) * hstride + (c - 1024));
      *(float4*)&xs[b][c] = v;
    }
  }
  __syncthreads();

  const int row = tid & 127;
  const int half = tid >> 7;
  const int g = row >> 5;
  const int kl = row & 31;
  const int jg = g * 512 + kt * 32 + kl;

  float a0 = 0.f, a1 = 0.f, a2 = 0.f, a3 = 0.f;
  const float4* x0 = (const float4*)&xs[half * 4 + 0][0];
  const float4* x1 = (const float4*)&xs[half * 4 + 1][0];
  const float4* x2 = (const float4*)&xs[half * 4 + 2][0];
  const float4* x3 = (const float4*)&xs[half * 4 + 3][0];

  const float4* wr = (const float4*)(Wih + (size_t)jg * 1024);
  #pragma unroll 4
  for (int c4 = 0; c4 < 256; ++c4) {
    float4 w = wr[c4];
    float4 v;
    v = x0[c4]; a0 += w.x*v.x + w.y*v.y + w.z*v.z + w.w*v.w;
    v = x1[c4]; a1 += w.x*v.x + w.y*v.y + w.z*v.z + w.w*v.w;
    v = x2[c4]; a2 += w.x*v.x + w.y*v.y + w.z*v.z + w.w*v.w;
    v = x3[c4]; a3 += w.x*v.x + w.y*v.y + w.z*v.z + w.w*v.w;
  }
  const float4* wr2 = (const float4*)(Whh + (size_t)jg * 512);
  #pragma unroll 4
  for (int c4 = 0; c4 < 128; ++c4) {
    float4 w = wr2[c4];
    float4 v;
    v = x0[256 + c4]; a0 += w.x*v.x + w.y*v.y + w.z*v.z + w.w*v.w;
    v = x1[256 + c4]; a1 += w.x*v.x + w.y*v.y + w.z*v.z + w.w*v.w;
    v = x2[256 + c4]; a2 += w.x*v.x + w.y*v.y + w.z*v.z + w.w*v.w;
    v = x3[256 + c4]; a3 += w.x*v.x + w.y*v.y + w.z*v.z + w.w*v.w;
  }
  float bias = bih[jg] + bhh[jg];
  gl[g][kl][half * 4 + 0] = a0 + bias;
  gl[g][kl][half * 4 + 1] = a1 + bias;
  gl[g][kl][half * 4 + 2] = a2 + bias;
  gl[g][kl][half * 4 + 3] = a3 + bias;
  __syncthreads();

  {
    const int b = tid >> 5;          // 0..7
    const int klc = tid & 31;
    const int k2 = kt * 32 + klc;
    float iv = sigm(gl[0][klc][b]);
    float fv = sigm(gl[1][klc][b]);
    float gv = tanhf(gl[2][klc][b]);
    float ov = sigm(gl[3][klc][b]);
    float cold = cprev[(size_t)(b0 + b) * 512 + k2];
    float cn = fv * cold + iv * gv;
    cnew[(size_t)(b0 + b) * 512 + k2] = cn;
    hout[(size_t)(b0 + b) * hostride + k2] = ov * tanhf(cn);
  }
}

// ---------------- bf16 MFMA GEMM: C[M=4096][N=32000] = A[M][512] * B[N][512]^T
// 128x128 tile, 4 waves (2x2), 64x64 per wave, K-step 32, double-buffered global_load_lds.
__global__ __launch_bounds__(256) void gemm_kernel(
    const unsigned short* __restrict__ A,
    const unsigned short* __restrict__ Bm,
    float* __restrict__ C)
{
  __shared__ unsigned short ldsA[2][128 * 32];
  __shared__ unsigned short ldsB[2][128 * 32];
  const int tid = threadIdx.x;
  const int lane = tid & 63;
  const int wid = tid >> 6;
  const int wm = wid >> 1, wn = wid & 1;
  const int m0 = blockIdx.y * 128;
  const int n0 = blockIdx.x * 128;
  const int srow = lane >> 2;          // 0..15
  const int scol = (lane & 3) * 8;     // bf16 elements

  f32x4 acc[4][4] = {};
  const int NK = 512 / 32;

  auto stage = [&](int kk, int buf) {
    const int k0 = kk * 32;
    #pragma unroll
    for (int c = 0; c < 2; ++c) {
      const int r = wid * 32 + c * 16;
      const unsigned short* sa = A  + (size_t)(m0 + r + srow) * 512 + k0 + scol;
      const unsigned short* sb = Bm + (size_t)(n0 + r + srow) * 512 + k0 + scol;
      __builtin_amdgcn_global_load_lds((const AS1 void*)sa, (AS3 void*)&ldsA[buf][r * 32], 16, 0, 0);
      __builtin_amdgcn_global_load_lds((const AS1 void*)sb, (AS3 void*)&ldsB[buf][r * 32], 16, 0, 0);
    }
  };

  stage(0, 0);
  __syncthreads();

  const int rl = lane & 15;
  const int kb = lane >> 4;

  for (int kk = 0; kk < NK; ++kk) {
    const int buf = kk & 1;
    if (kk + 1 < NK) stage(kk + 1, buf ^ 1);
    const bf16x8* Af = (const bf16x8*)&ldsA[buf][0];
    const bf16x8* Bf = (const bf16x8*)&ldsB[buf][0];
    bf16x8 av[4], bv[4];
    #pragma unroll
    for (int mi = 0; mi < 4; ++mi) av[mi] = Af[(wm * 64 + mi * 16 + rl) * 4 + kb];
    #pragma unroll
    for (int ni = 0; ni < 4; ++ni) bv[ni] = Bf[(wn * 64 + ni * 16 + rl) * 4 + kb];
    #pragma unroll
    for (int mi = 0; mi < 4; ++mi)
      #pragma unroll
      for (int ni = 0; ni < 4; ++ni)
        acc[mi][ni] = __builtin_amdgcn_mfma_f32_16x16x32_bf16(av[mi], bv[ni], acc[mi][ni], 0, 0, 0);
    __syncthreads();   // drains vmcnt (staging) + lgkm, then barrier
  }

  const int rb = (lane >> 4) * 4;
  #pragma unroll
  for (int mi = 0; mi < 4; ++mi)
    #pragma unroll
    for (int ni = 0; ni < 4; ++ni) {
      size_t rrow = (size_t)(m0 + wm * 64 + mi * 16 + rb);
      size_t col = (size_t)(n0 + wn * 64 + ni * 16 + rl);
      #pragma unroll
      for (int j = 0; j < 4; ++j)
        C[(rrow + j) * (size_t)V_ + col] = acc[mi][ni][j];
    }
}

// ---------------- in-place row log_softmax over V=32000 (8000 float4 per row)
__global__ __launch_bounds__(256) void logsoftmax_kernel(float* __restrict__ C) {
  const size_t row = blockIdx.x;
  float* p = C + row * (size_t)V_;
  const float4* p4 = (const float4*)p;
  const int tid = threadIdx.x, lane = tid & 63, wid = tid >> 6;
  __shared__ float red[4];

  float m = -INFINITY;
  for (int i = tid; i < 8000; i += 256) {
    float4 v = p4[i];
    m = fmaxf(m, fmaxf(fmaxf(v.x, v.y), fmaxf(v.z, v.w)));
  }
  #pragma unroll
  for (int off = 32; off > 0; off >>= 1) m = fmaxf(m, __shfl_xor(m, off));
  if (lane == 0) red[wid] = m;
  __syncthreads();
  m = fmaxf(fmaxf(red[0], red[1]), fmaxf(red[2], red[3]));
  __syncthreads();

  float s = 0.f;
  for (int i = tid; i < 8000; i += 256) {
    float4 v = p4[i];
    s += expf(v.x - m) + expf(v.y - m) + expf(v.z - m) + expf(v.w - m);
  }
  #pragma unroll
  for (int off = 32; off > 0; off >>= 1) s += __shfl_xor(s, off);
  if (lane == 0) red[wid] = s;
  __syncthreads();
  s = red[0] + red[1] + red[2] + red[3];
  float lse = m + logf(s);

  float4* w4 = (float4*)p;
  for (int i = tid; i < 8000; i += 256) {
    float4 v = p4[i];
    v.x -= lse; v.y -= lse; v.z -= lse; v.w -= lse;
    w4[i] = v;
  }
}

extern "C" void kernel_launch(void* const* d_in, const int* in_sizes, int n_in,
                              void* d_out, int out_size, void* d_ws, size_t ws_size,
                              hipStream_t stream) {
  const int*   dst  = (const int*)d_in[0];
  const float* E    = (const float*)d_in[1];
  const float* Wih  = (const float*)d_in[2];
  const float* Whh  = (const float*)d_in[3];
  const float* bih  = (const float*)d_in[4];
  const float* bhh  = (const float*)d_in[5];
  const float* h0   = (const float*)d_in[6];
  const float* c0   = (const float*)d_in[7];
  const float* out0 = (const float*)d_in[8];
  float* C = (float*)d_out;

  char* ws = (char*)d_ws;
  float* emb  = (float*)ws;                              // 8 MB  [T*B][512]
  float* outs = (float*)(ws + (8u << 20));               // 8 MB  [B][T][512] (row b*T+t)
  float* cb0  = (float*)(ws + (16u << 20));              // 64 KB
  float* cb1  = cb0 + B_ * H_;                           // 64 KB
  unsigned short* Abf = (unsigned short*)(ws + (17u << 20));  // 4 MB
  unsigned short* Ebf = (unsigned short*)(ws + (21u << 20));  // 32.8 MB

  embed_kernel<<<dim3(T_ * B_), dim3(64), 0, stream>>>(dst, E, emb);
  cvt_kernel<<<dim3(2048), dim3(256), 0, stream>>>(E, Ebf, V_ * D_ / 4);

  const int HS = T_ * H_;   // 65536, b-stride in outs
  for (int t = 0; t < T_; ++t) {
    const float* hp; int hs; const float* op; int os; const float* cp;
    if (t == 0) { hp = h0; hs = H_; op = out0; os = H_; cp = c0; }
    else {
      hp = outs + (size_t)(t - 1) * H_; hs = HS;
      op = hp; os = HS;
      cp = (t & 1) ? cb0 : cb1;
    }
    float* cn = (t & 1) ? cb1 : cb0;
    lstm_step_kernel<<<dim3(16, 4), dim3(256), 0, stream>>>(
        t, emb, Wih, Whh, bih, bhh, hp, hs, op, os, cp, cn,
        outs + (size_t)t * H_, HS);
  }

  cvt_kernel<<<dim3(512), dim3(256), 0, stream>>>(outs, Abf, B_ * T_ * H_ / 4);
  gemm_kernel<<<dim3(V_ / 128, (B_ * T_) / 128), dim3(256), 0, stream>>>(Abf, Ebf, C);
  logsoftmax_kernel<<<dim3(B_ * T_), dim3(256), 0, stream>>>(C);
}

// Round 2
// 1674.903 us; speedup vs baseline: 4.0553x; 4.0553x over previous
//
#include <hip/hip_runtime.h>
#include <hip/hip_bf16.h>
#include <math.h>

#define B_ 32
#define T_ 128
#define V_ 32000
#define D_ 512
#define H_ 512

typedef __attribute__((ext_vector_type(8))) short bf16x8;
typedef __attribute__((ext_vector_type(4))) float f32x4;

#define AS1 __attribute__((address_space(1)))
#define AS3 __attribute__((address_space(3)))

__device__ __forceinline__ unsigned short f2bf(float x) {
  unsigned int b = __float_as_uint(x);
  return (unsigned short)((b + 0x7FFFu + ((b >> 16) & 1u)) >> 16);
}
__device__ __forceinline__ float bf2f(unsigned short u) {
  return __uint_as_float(((unsigned int)u) << 16);
}
__device__ __forceinline__ float sigm(float x) { return 1.0f / (1.0f + expf(-x)); }

// ---------------- embedding gather -> bf16: embbf[t*32+b][:] = bf16(E[dst[b][t]][:])
__global__ __launch_bounds__(64) void embed_bf_kernel(const int* __restrict__ dst,
                                                      const float* __restrict__ E,
                                                      unsigned short* __restrict__ embbf) {
  int rt = blockIdx.x;           // t*32 + b
  int t = rt >> 5, b = rt & 31;
  int v = dst[b * T_ + t];
  const float4* src = (const float4*)(E + (size_t)v * D_);
  ushort4* d = (ushort4*)(embbf + (size_t)rt * D_);
  #pragma unroll
  for (int r = 0; r < 2; ++r) {
    float4 x = src[threadIdx.x + r * 64];
    ushort4 o; o.x = f2bf(x.x); o.y = f2bf(x.y); o.z = f2bf(x.z); o.w = f2bf(x.w);
    d[threadIdx.x + r * 64] = o;
  }
}

// ---------------- generic f32 -> bf16
__global__ void cvt_kernel(const float* __restrict__ in, unsigned short* __restrict__ out, int n4) {
  int stride = gridDim.x * blockDim.x;
  for (int i = blockIdx.x * blockDim.x + threadIdx.x; i < n4; i += stride) {
    float4 v = ((const float4*)in)[i];
    ushort4 o; o.x = f2bf(v.x); o.y = f2bf(v.y); o.z = f2bf(v.z); o.w = f2bf(v.w);
    ((ushort4*)out)[i] = o;
  }
}

// ---------------- W1bf[r][c] = bf16(Wih[r][c]), c<512 (row stride 1024)
__global__ void cvt_w1_kernel(const float* __restrict__ Wih, unsigned short* __restrict__ W1bf, int n4) {
  int stride = gridDim.x * blockDim.x;
  for (int i = blockIdx.x * blockDim.x + threadIdx.x; i < n4; i += stride) {
    int flat = i * 4;
    int r = flat >> 9, c = flat & 511;
    float4 v = *(const float4*)(Wih + (size_t)r * 1024 + c);
    ushort4 o; o.x = f2bf(v.x); o.y = f2bf(v.y); o.z = f2bf(v.z); o.w = f2bf(v.w);
    ((ushort4*)W1bf)[i] = o;
  }
}

// ---------------- Wr[r][c] = Wih[r][512+c] + Whh[r][c]  (f32)
__global__ void wr_prep_kernel(const float* __restrict__ Wih, const float* __restrict__ Whh,
                               float* __restrict__ Wr, int n4) {
  int stride = gridDim.x * blockDim.x;
  for (int i = blockIdx.x * blockDim.x + threadIdx.x; i < n4; i += stride) {
    int flat = i * 4;
    int r = flat >> 9, c = flat & 511;
    float4 a = *(const float4*)(Wih + (size_t)r * 1024 + 512 + c);
    float4 b = ((const float4*)Whh)[i];
    float4 o; o.x = a.x + b.x; o.y = a.y + b.y; o.z = a.z + b.z; o.w = a.w + b.w;
    ((float4*)Wr)[i] = o;
  }
}

__global__ void bias_prep_kernel(const float* __restrict__ bih, const float* __restrict__ bhh,
                                 float* __restrict__ bias) {
  int i = blockIdx.x * blockDim.x + threadIdx.x;
  if (i < 2048) bias[i] = bih[i] + bhh[i];
}

// ---------------- preAT[:, 0:32] += (out0 - h0) @ W2^T   (bf16 RMW, runs after pre-GEMM)
__global__ __launch_bounds__(256) void delta0_kernel(const float* __restrict__ Wih,
                                                     const float* __restrict__ out0,
                                                     const float* __restrict__ h0,
                                                     unsigned short* __restrict__ preAT) {
  const int r = blockIdx.x;
  const int tid = threadIdx.x;
  const int b = tid >> 3, seg = tid & 7;
  __shared__ float red[32][9];
  const float4* o4 = (const float4*)(out0 + (size_t)b * 512 + seg * 64);
  const float4* h4 = (const float4*)(h0 + (size_t)b * 512 + seg * 64);
  const float4* w4 = (const float4*)(Wih + (size_t)r * 1024 + 512 + seg * 64);
  float s = 0.f;
  #pragma unroll
  for (int j = 0; j < 16; ++j) {
    float4 o = o4[j], h = h4[j], w = w4[j];
    s += (o.x - h.x) * w.x + (o.y - h.y) * w.y + (o.z - h.z) * w.z + (o.w - h.w) * w.w;
  }
  red[b][seg] = s;
  __syncthreads();
  if (tid < 32) {
    float t = 0.f;
    #pragma unroll
    for (int j = 0; j < 8; ++j) t += red[tid][j];
    unsigned short* p = preAT + (size_t)r * 4096 + tid;
    *p = f2bf(bf2f(*p) + t);
  }
}

// ---------------- one LSTM step (cheap recurrent part only)
// grid(256): block owns k = {bid*2, bid*2+1} across all 4 gates (8 gate-rows).
__global__ __launch_bounds__(256) void lstm_step2_kernel(
    int t,
    const unsigned short* __restrict__ preAT, // [2048][4096] bf16 (+bias NOT included)
    const float* __restrict__ Wr,             // [2048][512] f32
    const float* __restrict__ bias,           // [2048]
    const float* __restrict__ h_in,           // [32][512] f32
    float* __restrict__ h_out,                // [32][512] f32
    float* __restrict__ c_buf,                // [32][512] f32 (RMW)
    unsigned short* __restrict__ Abf)         // [32*T][512] bf16, row b*T+t
{
  __shared__ float h_lds[32][516];
  __shared__ float wr_lds[8][512];
  __shared__ float gbuf[8][33];
  const int tid = threadIdx.x, bid = blockIdx.x;

  // stage Wr slice: 8 rows x 512 = 1024 float4
  for (int idx = tid; idx < 1024; idx += 256) {
    int r = idx >> 7, c4 = idx & 127;
    int grow = (r >> 1) * 512 + bid * 2 + (r & 1);
    *(float4*)&wr_lds[r][c4 * 4] = *(const float4*)(Wr + (size_t)grow * 512 + c4 * 4);
  }
  // stage h: 16384 f32, coalesced global reads
  #pragma unroll
  for (int j = 0; j < 16; ++j) {
    int F = (j * 256 + tid) * 4;
    float4 v = *(const float4*)(h_in + F);
    *(float4*)&h_lds[F >> 9][F & 511] = v;
  }
  __syncthreads();

  const int b = tid & 31, rl = tid >> 5;
  const int grow = (rl >> 1) * 512 + bid * 2 + (rl & 1);
  const float4* hp = (const float4*)&h_lds[b][0];
  const float4* wp = (const float4*)&wr_lds[rl][0];
  float acc = 0.f;
  #pragma unroll 8
  for (int c4 = 0; c4 < 128; ++c4) {
    float4 hv = hp[c4], wv = wp[c4];
    acc += hv.x * wv.x + hv.y * wv.y + hv.z * wv.z + hv.w * wv.w;
  }
  acc += bf2f(preAT[(size_t)grow * 4096 + t * 32 + b]) + bias[grow];
  gbuf[rl][b] = acc;
  __syncthreads();

  if (tid < 64) {
    int bb = tid & 31, kl = tid >> 5;
    int k = bid * 2 + kl;
    float iv = sigm(gbuf[0 + kl][bb]);
    float fv = sigm(gbuf[2 + kl][bb]);
    float gv = tanhf(gbuf[4 + kl][bb]);
    float ov = sigm(gbuf[6 + kl][bb]);
    size_t ci = (size_t)bb * 512 + k;
    float cn = fv * c_buf[ci] + iv * gv;
    c_buf[ci] = cn;
    float hn = ov * tanhf(cn);
    h_out[ci] = hn;
    Abf[((size_t)bb * T_ + t) * 512 + k] = f2bf(hn);
  }
}

// ---------------- bf16 MFMA GEMM core (128x128 tile, 4 waves, K=512)
__global__ __launch_bounds__(256) void gemm_kernel(
    const unsigned short* __restrict__ A,
    const unsigned short* __restrict__ Bm,
    float* __restrict__ C)
{
  __shared__ unsigned short ldsA[2][128 * 32];
  __shared__ unsigned short ldsB[2][128 * 32];
  const int tid = threadIdx.x;
  const int lane = tid & 63;
  const int wid = tid >> 6;
  const int wm = wid >> 1, wn = wid & 1;
  const int m0 = blockIdx.y * 128;
  const int n0 = blockIdx.x * 128;
  const int srow = lane >> 2;
  const int scol = (lane & 3) * 8;

  f32x4 acc[4][4] = {};
  const int NK = 512 / 32;

  auto stage = [&](int kk, int buf) {
    const int k0 = kk * 32;
    #pragma unroll
    for (int c = 0; c < 2; ++c) {
      const int r = wid * 32 + c * 16;
      const unsigned short* sa = A  + (size_t)(m0 + r + srow) * 512 + k0 + scol;
      const unsigned short* sb = Bm + (size_t)(n0 + r + srow) * 512 + k0 + scol;
      __builtin_amdgcn_global_load_lds((const AS1 void*)sa, (AS3 void*)&ldsA[buf][r * 32], 16, 0, 0);
      __builtin_amdgcn_global_load_lds((const AS1 void*)sb, (AS3 void*)&ldsB[buf][r * 32], 16, 0, 0);
    }
  };

  stage(0, 0);
  __syncthreads();

  const int rl = lane & 15;
  const int kb = lane >> 4;

  for (int kk = 0; kk < NK; ++kk) {
    const int buf = kk & 1;
    if (kk + 1 < NK) stage(kk + 1, buf ^ 1);
    const bf16x8* Af = (const bf16x8*)&ldsA[buf][0];
    const bf16x8* Bf = (const bf16x8*)&ldsB[buf][0];
    bf16x8 av[4], bv[4];
    #pragma unroll
    for (int mi = 0; mi < 4; ++mi) av[mi] = Af[(wm * 64 + mi * 16 + rl) * 4 + kb];
    #pragma unroll
    for (int ni = 0; ni < 4; ++ni) bv[ni] = Bf[(wn * 64 + ni * 16 + rl) * 4 + kb];
    #pragma unroll
    for (int mi = 0; mi < 4; ++mi)
      #pragma unroll
      for (int ni = 0; ni < 4; ++ni)
        acc[mi][ni] = __builtin_amdgcn_mfma_f32_16x16x32_bf16(av[mi], bv[ni], acc[mi][ni], 0, 0, 0);
    __syncthreads();
  }

  const int rb = (lane >> 4) * 4;
  #pragma unroll
  for (int mi = 0; mi < 4; ++mi)
    #pragma unroll
    for (int ni = 0; ni < 4; ++ni) {
      size_t rrow = (size_t)(m0 + wm * 64 + mi * 16 + rb);
      size_t col = (size_t)(n0 + wn * 64 + ni * 16 + rl);
      #pragma unroll
      for (int j = 0; j < 4; ++j)
        C[(rrow + j) * (size_t)V_ + col] = acc[mi][ni][j];
    }
}

// ---------------- pre-GEMM: preAT[2048][4096] (bf16, transposed store) = W1 x emb^T
// A = embbf [4096][512], B = W1bf [2048][512]; out[col n][row m].
__global__ __launch_bounds__(256) void gemm_pre_kernel(
    const unsigned short* __restrict__ A,
    const unsigned short* __restrict__ Bm,
    unsigned short* __restrict__ preAT)
{
  __shared__ unsigned short ldsA[2][128 * 32];
  __shared__ unsigned short ldsB[2][128 * 32];
  const int tid = threadIdx.x;
  const int lane = tid & 63;
  const int wid = tid >> 6;
  const int wm = wid >> 1, wn = wid & 1;
  const int m0 = blockIdx.y * 128;
  const int n0 = blockIdx.x * 128;
  const int srow = lane >> 2;
  const int scol = (lane & 3) * 8;

  f32x4 acc[4][4] = {};
  const int NK = 512 / 32;

  auto stage = [&](int kk, int buf) {
    const int k0 = kk * 32;
    #pragma unroll
    for (int c = 0; c < 2; ++c) {
      const int r = wid * 32 + c * 16;
      const unsigned short* sa = A  + (size_t)(m0 + r + srow) * 512 + k0 + scol;
      const unsigned short* sb = Bm + (size_t)(n0 + r + srow) * 512 + k0 + scol;
      __builtin_amdgcn_global_load_lds((const AS1 void*)sa, (AS3 void*)&ldsA[buf][r * 32], 16, 0, 0);
      __builtin_amdgcn_global_load_lds((const AS1 void*)sb, (AS3 void*)&ldsB[buf][r * 32], 16, 0, 0);
    }
  };

  stage(0, 0);
  __syncthreads();

  const int rl = lane & 15;
  const int kb = lane >> 4;

  for (int kk = 0; kk < NK; ++kk) {
    const int buf = kk & 1;
    if (kk + 1 < NK) stage(kk + 1, buf ^ 1);
    const bf16x8* Af = (const bf16x8*)&ldsA[buf][0];
    const bf16x8* Bf = (const bf16x8*)&ldsB[buf][0];
    bf16x8 av[4], bv[4];
    #pragma unroll
    for (int mi = 0; mi < 4; ++mi) av[mi] = Af[(wm * 64 + mi * 16 + rl) * 4 + kb];
    #pragma unroll
    for (int ni = 0; ni < 4; ++ni) bv[ni] = Bf[(wn * 64 + ni * 16 + rl) * 4 + kb];
    #pragma unroll
    for (int mi = 0; mi < 4; ++mi)
      #pragma unroll
      for (int ni = 0; ni < 4; ++ni)
        acc[mi][ni] = __builtin_amdgcn_mfma_f32_16x16x32_bf16(av[mi], bv[ni], acc[mi][ni], 0, 0, 0);
    __syncthreads();
  }

  const int rb = (lane >> 4) * 4;
  #pragma unroll
  for (int mi = 0; mi < 4; ++mi)
    #pragma unroll
    for (int ni = 0; ni < 4; ++ni) {
      int mbase = m0 + wm * 64 + mi * 16 + rb;
      int col   = n0 + wn * 64 + ni * 16 + rl;
      ushort4 o;
      o.x = f2bf(acc[mi][ni][0]); o.y = f2bf(acc[mi][ni][1]);
      o.z = f2bf(acc[mi][ni][2]); o.w = f2bf(acc[mi][ni][3]);
      *(ushort4*)&preAT[(size_t)col * 4096 + mbase] = o;
    }
}

// ---------------- in-place row log_softmax over V=32000
__global__ __launch_bounds__(256) void logsoftmax_kernel(float* __restrict__ C) {
  const size_t row = blockIdx.x;
  float* p = C + row * (size_t)V_;
  const float4* p4 = (const float4*)p;
  const int tid = threadIdx.x, lane = tid & 63, wid = tid >> 6;
  __shared__ float red[4];

  float m = -INFINITY;
  for (int i = tid; i < 8000; i += 256) {
    float4 v = p4[i];
    m = fmaxf(m, fmaxf(fmaxf(v.x, v.y), fmaxf(v.z, v.w)));
  }
  #pragma unroll
  for (int off = 32; off > 0; off >>= 1) m = fmaxf(m, __shfl_xor(m, off));
  if (lane == 0) red[wid] = m;
  __syncthreads();
  m = fmaxf(fmaxf(red[0], red[1]), fmaxf(red[2], red[3]));
  __syncthreads();

  float s = 0.f;
  for (int i = tid; i < 8000; i += 256) {
    float4 v = p4[i];
    s += expf(v.x - m) + expf(v.y - m) + expf(v.z - m) + expf(v.w - m);
  }
  #pragma unroll
  for (int off = 32; off > 0; off >>= 1) s += __shfl_xor(s, off);
  if (lane == 0) red[wid] = s;
  __syncthreads();
  s = red[0] + red[1] + red[2] + red[3];
  float lse = m + logf(s);

  float4* w4 = (float4*)p;
  for (int i = tid; i < 8000; i += 256) {
    float4 v = p4[i];
    v.x -= lse; v.y -= lse; v.z -= lse; v.w -= lse;
    w4[i] = v;
  }
}

extern "C" void kernel_launch(void* const* d_in, const int* in_sizes, int n_in,
                              void* d_out, int out_size, void* d_ws, size_t ws_size,
                              hipStream_t stream) {
  const int*   dst  = (const int*)d_in[0];
  const float* E    = (const float*)d_in[1];
  const float* Wih  = (const float*)d_in[2];
  const float* Whh  = (const float*)d_in[3];
  const float* bih  = (const float*)d_in[4];
  const float* bhh  = (const float*)d_in[5];
  const float* h0   = (const float*)d_in[6];
  const float* c0   = (const float*)d_in[7];
  const float* out0 = (const float*)d_in[8];
  float* C = (float*)d_out;

  char* ws = (char*)d_ws;
  unsigned short* Ebf   = (unsigned short*)(ws);                         // 32.77 MB
  unsigned short* preAT = (unsigned short*)(ws + (size_t)33554432);      // 16.78 MB
  float*          Wr    = (float*)(ws + (size_t)50331648);               // 4.19 MB
  unsigned short* embbf = (unsigned short*)(ws + (size_t)54525952);      // 4.19 MB
  unsigned short* W1bf  = (unsigned short*)(ws + (size_t)58720256);      // 2.10 MB
  unsigned short* Abf   = (unsigned short*)(ws + (size_t)60817408);      // 4.19 MB
  float*          hbuf0 = (float*)(ws + (size_t)65011712);               // 64 KB
  float*          hbuf1 = hbuf0 + B_ * H_;
  float*          cbuf  = hbuf1 + B_ * H_;
  float*          bias  = cbuf + B_ * H_;                                // 8 KB

  // --- precompute ---
  embed_bf_kernel<<<dim3(T_ * B_), dim3(64), 0, stream>>>(dst, E, embbf);
  cvt_kernel<<<dim3(2048), dim3(256), 0, stream>>>(E, Ebf, V_ * D_ / 4);
  cvt_w1_kernel<<<dim3(256), dim3(256), 0, stream>>>(Wih, W1bf, 2048 * 512 / 4);
  wr_prep_kernel<<<dim3(256), dim3(256), 0, stream>>>(Wih, Whh, Wr, 2048 * 512 / 4);
  bias_prep_kernel<<<dim3(8), dim3(256), 0, stream>>>(bih, bhh, bias);

  // preAT = W1 x emb^T  (transposed bf16 store)
  gemm_pre_kernel<<<dim3(2048 / 128, 4096 / 128), dim3(256), 0, stream>>>(embbf, W1bf, preAT);
  // t=0 correction
  delta0_kernel<<<dim3(2048), dim3(256), 0, stream>>>(Wih, out0, h0, preAT);

  hipMemcpyAsync(hbuf0, h0, (size_t)B_ * H_ * 4, hipMemcpyDeviceToDevice, stream);
  hipMemcpyAsync(cbuf,  c0, (size_t)B_ * H_ * 4, hipMemcpyDeviceToDevice, stream);

  // --- recurrence ---
  for (int t = 0; t < T_; ++t) {
    const float* hin = (t & 1) ? hbuf1 : hbuf0;
    float*       hout = (t & 1) ? hbuf0 : hbuf1;
    lstm_step2_kernel<<<dim3(256), dim3(256), 0, stream>>>(
        t, preAT, Wr, bias, hin, hout, cbuf, Abf);
  }

  // --- projection + log softmax ---
  gemm_kernel<<<dim3(V_ / 128, (B_ * T_) / 128), dim3(256), 0, stream>>>(Abf, Ebf, C);
  logsoftmax_kernel<<<dim3(B_ * T_), dim3(256), 0, stream>>>(C);
}

// Round 3
// 1305.879 us; speedup vs baseline: 5.2013x; 1.2826x over previous
//
#include <hip/hip_runtime.h>
#include <hip/hip_bf16.h>
#include <math.h>

#define B_ 32
#define T_ 128
#define V_ 32000
#define D_ 512
#define H_ 512

typedef __attribute__((ext_vector_type(8))) short bf16x8;
typedef __attribute__((ext_vector_type(4))) float f32x4;

#define AS1 __attribute__((address_space(1)))
#define AS3 __attribute__((address_space(3)))

__device__ __forceinline__ unsigned short f2bf(float x) {
  unsigned int b = __float_as_uint(x);
  return (unsigned short)((b + 0x7FFFu + ((b >> 16) & 1u)) >> 16);
}
__device__ __forceinline__ float bf2f(unsigned short u) {
  return __uint_as_float(((unsigned int)u) << 16);
}
__device__ __forceinline__ float sigm(float x) { return 1.0f / (1.0f + expf(-x)); }

// ---------------- embedding gather -> bf16: embbf[t*32+b][:] = bf16(E[dst[b][t]][:])
__global__ __launch_bounds__(64) void embed_bf_kernel(const int* __restrict__ dst,
                                                      const float* __restrict__ E,
                                                      unsigned short* __restrict__ embbf) {
  int rt = blockIdx.x;           // t*32 + b
  int t = rt >> 5, b = rt & 31;
  int v = dst[b * T_ + t];
  const float4* src = (const float4*)(E + (size_t)v * D_);
  ushort4* d = (ushort4*)(embbf + (size_t)rt * D_);
  #pragma unroll
  for (int r = 0; r < 2; ++r) {
    float4 x = src[threadIdx.x + r * 64];
    ushort4 o; o.x = f2bf(x.x); o.y = f2bf(x.y); o.z = f2bf(x.z); o.w = f2bf(x.w);
    d[threadIdx.x + r * 64] = o;
  }
}

// ---------------- generic f32 -> bf16
__global__ void cvt_kernel(const float* __restrict__ in, unsigned short* __restrict__ out, int n4) {
  int stride = gridDim.x * blockDim.x;
  for (int i = blockIdx.x * blockDim.x + threadIdx.x; i < n4; i += stride) {
    float4 v = ((const float4*)in)[i];
    ushort4 o; o.x = f2bf(v.x); o.y = f2bf(v.y); o.z = f2bf(v.z); o.w = f2bf(v.w);
    ((ushort4*)out)[i] = o;
  }
}

// ---------------- W1bf[r][c] = bf16(Wih[r][c]), c<512 (row stride 1024)
__global__ void cvt_w1_kernel(const float* __restrict__ Wih, unsigned short* __restrict__ W1bf, int n4) {
  int stride = gridDim.x * blockDim.x;
  for (int i = blockIdx.x * blockDim.x + threadIdx.x; i < n4; i += stride) {
    int flat = i * 4;
    int r = flat >> 9, c = flat & 511;
    float4 v = *(const float4*)(Wih + (size_t)r * 1024 + c);
    ushort4 o; o.x = f2bf(v.x); o.y = f2bf(v.y); o.z = f2bf(v.z); o.w = f2bf(v.w);
    ((ushort4*)W1bf)[i] = o;
  }
}

// ---------------- Wrs[grow][perm(k)] = bf16(Wih[grow][512+k] + Whh[grow][k])
// per-row 16B-chunk swizzle: chunk' = chunk ^ (grow&7)  (T2 st-swizzle, pre-applied in global)
__global__ void wr_prep_swz_kernel(const float* __restrict__ Wih, const float* __restrict__ Whh,
                                   unsigned short* __restrict__ Wrs, int n4) {
  int stride = gridDim.x * blockDim.x;
  for (int i = blockIdx.x * blockDim.x + threadIdx.x; i < n4; i += stride) {
    int flat = i * 4;
    int grow = flat >> 9, k = flat & 511;
    float4 a = *(const float4*)(Wih + (size_t)grow * 1024 + 512 + k);
    float4 b = ((const float4*)Whh)[i];
    ushort4 o;
    o.x = f2bf(a.x + b.x); o.y = f2bf(a.y + b.y); o.z = f2bf(a.z + b.z); o.w = f2bf(a.w + b.w);
    int chunk = (k >> 3) ^ (grow & 7);
    *(ushort4*)(Wrs + (size_t)grow * 512 + chunk * 8 + (k & 7)) = o;
  }
}

// ---------------- pre-GEMM: preA2[t][grow][b] = bf16(emb[t*32+b] . W1[grow] + bias[grow])
// A = embbf [4096][512], B = W1bf [2048][512]
__global__ __launch_bounds__(256) void gemm_pre_kernel(
    const unsigned short* __restrict__ A,
    const unsigned short* __restrict__ Bm,
    const float* __restrict__ bih, const float* __restrict__ bhh,
    unsigned short* __restrict__ preA2)
{
  __shared__ unsigned short ldsA[2][128 * 32];
  __shared__ unsigned short ldsB[2][128 * 32];
  const int tid = threadIdx.x;
  const int lane = tid & 63;
  const int wid = tid >> 6;
  const int wm = wid >> 1, wn = wid & 1;
  const int m0 = blockIdx.y * 128;
  const int n0 = blockIdx.x * 128;
  const int srow = lane >> 2;
  const int scol = (lane & 3) * 8;

  f32x4 acc[4][4] = {};
  const int NK = 512 / 32;

  auto stage = [&](int kk, int buf) {
    const int k0 = kk * 32;
    #pragma unroll
    for (int c = 0; c < 2; ++c) {
      const int r = wid * 32 + c * 16;
      const unsigned short* sa = A  + (size_t)(m0 + r + srow) * 512 + k0 + scol;
      const unsigned short* sb = Bm + (size_t)(n0 + r + srow) * 512 + k0 + scol;
      __builtin_amdgcn_global_load_lds((const AS1 void*)sa, (AS3 void*)&ldsA[buf][r * 32], 16, 0, 0);
      __builtin_amdgcn_global_load_lds((const AS1 void*)sb, (AS3 void*)&ldsB[buf][r * 32], 16, 0, 0);
    }
  };

  stage(0, 0);
  __syncthreads();

  const int rl = lane & 15;
  const int kb = lane >> 4;

  for (int kk = 0; kk < NK; ++kk) {
    const int buf = kk & 1;
    if (kk + 1 < NK) stage(kk + 1, buf ^ 1);
    const bf16x8* Af = (const bf16x8*)&ldsA[buf][0];
    const bf16x8* Bf = (const bf16x8*)&ldsB[buf][0];
    bf16x8 av[4], bv[4];
    #pragma unroll
    for (int mi = 0; mi < 4; ++mi) av[mi] = Af[(wm * 64 + mi * 16 + rl) * 4 + kb];
    #pragma unroll
    for (int ni = 0; ni < 4; ++ni) bv[ni] = Bf[(wn * 64 + ni * 16 + rl) * 4 + kb];
    #pragma unroll
    for (int mi = 0; mi < 4; ++mi)
      #pragma unroll
      for (int ni = 0; ni < 4; ++ni)
        acc[mi][ni] = __builtin_amdgcn_mfma_f32_16x16x32_bf16(av[mi], bv[ni], acc[mi][ni], 0, 0, 0);
    __syncthreads();
  }

  const int rb = (lane >> 4) * 4;
  #pragma unroll
  for (int mi = 0; mi < 4; ++mi)
    #pragma unroll
    for (int ni = 0; ni < 4; ++ni) {
      int mbase = m0 + wm * 64 + mi * 16 + rb;
      int col   = n0 + wn * 64 + ni * 16 + rl;
      float bb = bih[col] + bhh[col];
      ushort4 o;
      o.x = f2bf(acc[mi][ni][0] + bb); o.y = f2bf(acc[mi][ni][1] + bb);
      o.z = f2bf(acc[mi][ni][2] + bb); o.w = f2bf(acc[mi][ni][3] + bb);
      *(ushort4*)&preA2[((size_t)(mbase >> 5) * 2048 + col) * 32 + (mbase & 31)] = o;
    }
}

// ---------------- preA2[t=0][r][:] += (out0 - h0) @ W2^T
__global__ __launch_bounds__(256) void delta0_kernel(const float* __restrict__ Wih,
                                                     const float* __restrict__ out0,
                                                     const float* __restrict__ h0,
                                                     unsigned short* __restrict__ preA2) {
  const int r = blockIdx.x;
  const int tid = threadIdx.x;
  const int b = tid >> 3, seg = tid & 7;
  __shared__ float red[32][9];
  const float4* o4 = (const float4*)(out0 + (size_t)b * 512 + seg * 64);
  const float4* h4 = (const float4*)(h0 + (size_t)b * 512 + seg * 64);
  const float4* w4 = (const float4*)(Wih + (size_t)r * 1024 + 512 + seg * 64);
  float s = 0.f;
  #pragma unroll
  for (int j = 0; j < 16; ++j) {
    float4 o = o4[j], h = h4[j], w = w4[j];
    s += (o.x - h.x) * w.x + (o.y - h.y) * w.y + (o.z - h.z) * w.z + (o.w - h.w) * w.w;
  }
  red[b][seg] = s;
  __syncthreads();
  if (tid < 32) {
    float t = 0.f;
    #pragma unroll
    for (int j = 0; j < 8; ++j) t += red[tid][j];
    unsigned short* p = preA2 + (size_t)r * 32 + tid;
    *p = f2bf(bf2f(*p) + t);
  }
}

// ---------------- MFMA LSTM step: gates = Wr . h^T  (64 blocks own 8 k-slots x 4 gates)
__global__ __launch_bounds__(256) void lstm_step3_kernel(
    int t,
    const unsigned short* __restrict__ Wrs,   // [2048][512] bf16, chunk-swizzled rows
    const unsigned short* __restrict__ preA2, // [T][2048][32] bf16 (bias folded)
    const unsigned short* __restrict__ h_in,  // [32][512] bf16
    unsigned short* __restrict__ h_out,       // [32][512] bf16
    float* __restrict__ c_buf,                // [32][512] f32 (block-private slices)
    unsigned short* __restrict__ Abf)         // [B*T][512] bf16
{
  __shared__ unsigned short wlds[32 * 512];   // 32 KB
  __shared__ float gl[32][33];
  const int tid = threadIdx.x;
  const int bid = blockIdx.x;                 // k-slot base = bid*8
  const int lane = tid & 63, wid = tid >> 6;

  // stage 32 W rows (1 row = 1024B = one wave-wide 16B/lane load), linear LDS dest
  #pragma unroll
  for (int it = 0; it < 8; ++it) {
    int r = it * 4 + wid;                     // LDS row 0..31, wave-uniform
    int grow = (r >> 3) * 512 + bid * 8 + (r & 7);
    const unsigned short* src = Wrs + (size_t)grow * 512 + lane * 8;  // pre-swizzled source
    __builtin_amdgcn_global_load_lds((const AS1 void*)src, (AS3 void*)&wlds[r * 512], 16, 0, 0);
  }
  __syncthreads();

  // 4 waves = (rowtile, btile) in 2x2; full K=512 per wave
  const int rt = wid >> 1, bt = wid & 1;
  const int rl = lane & 15, q = lane >> 4;
  const int row = rt * 16 + rl;
  const char* wbase = (const char*)wlds + row * 1024;
  const int rx = (row & 7) << 4;
  f32x4 acc = {};
  #pragma unroll
  for (int kk = 0; kk < 16; ++kk) {
    const int kloc = kk * 32 + q * 8;
    bf16x8 av = *(const bf16x8*)(wbase + ((kloc * 2) ^ rx));          // swizzled read
    bf16x8 bv = *(const bf16x8*)(h_in + (size_t)(bt * 16 + rl) * 512 + kloc);
    acc = __builtin_amdgcn_mfma_f32_16x16x32_bf16(av, bv, acc, 0, 0, 0);
  }
  #pragma unroll
  for (int j = 0; j < 4; ++j)
    gl[rt * 16 + q * 4 + j][bt * 16 + rl] = acc[j];
  __syncthreads();

  {
    const int b = tid >> 3, k = tid & 7;
    const int kg = bid * 8 + k;
    const size_t pbase = (size_t)t * 2048 * 32;
    float g0 = gl[0 * 8 + k][b] + bf2f(preA2[pbase + (size_t)(0 * 512 + kg) * 32 + b]);
    float g1 = gl[1 * 8 + k][b] + bf2f(preA2[pbase + (size_t)(1 * 512 + kg) * 32 + b]);
    float g2 = gl[2 * 8 + k][b] + bf2f(preA2[pbase + (size_t)(2 * 512 + kg) * 32 + b]);
    float g3 = gl[3 * 8 + k][b] + bf2f(preA2[pbase + (size_t)(3 * 512 + kg) * 32 + b]);
    float iv = sigm(g0), fv = sigm(g1), gv = tanhf(g2), ov = sigm(g3);
    const size_t ci = (size_t)b * 512 + kg;
    float cn = fv * c_buf[ci] + iv * gv;
    c_buf[ci] = cn;
    float hn = ov * tanhf(cn);
    unsigned short hb = f2bf(hn);
    h_out[ci] = hb;
    Abf[((size_t)b * T_ + t) * 512 + kg] = hb;
  }
}

// ---------------- projection GEMM + per-tile softmax partials
__global__ __launch_bounds__(256) void gemm_kernel(
    const unsigned short* __restrict__ A,
    const unsigned short* __restrict__ Bm,
    float* __restrict__ C,
    float* __restrict__ pmax, float* __restrict__ psum)
{
  __shared__ unsigned short ldsA[2][128 * 32];
  __shared__ unsigned short ldsB[2][128 * 32];
  __shared__ float smax[2][128];
  __shared__ float ssum[2][128];
  const int tid = threadIdx.x;
  const int lane = tid & 63;
  const int wid = tid >> 6;
  const int wm = wid >> 1, wn = wid & 1;
  const int m0 = blockIdx.y * 128;
  const int n0 = blockIdx.x * 128;
  const int srow = lane >> 2;
  const int scol = (lane & 3) * 8;

  f32x4 acc[4][4] = {};
  const int NK = 512 / 32;

  auto stage = [&](int kk, int buf) {
    const int k0 = kk * 32;
    #pragma unroll
    for (int c = 0; c < 2; ++c) {
      const int r = wid * 32 + c * 16;
      const unsigned short* sa = A  + (size_t)(m0 + r + srow) * 512 + k0 + scol;
      const unsigned short* sb = Bm + (size_t)(n0 + r + srow) * 512 + k0 + scol;
      __builtin_amdgcn_global_load_lds((const AS1 void*)sa, (AS3 void*)&ldsA[buf][r * 32], 16, 0, 0);
      __builtin_amdgcn_global_load_lds((const AS1 void*)sb, (AS3 void*)&ldsB[buf][r * 32], 16, 0, 0);
    }
  };

  stage(0, 0);
  __syncthreads();

  const int rl = lane & 15;
  const int kb = lane >> 4;

  for (int kk = 0; kk < NK; ++kk) {
    const int buf = kk & 1;
    if (kk + 1 < NK) stage(kk + 1, buf ^ 1);
    const bf16x8* Af = (const bf16x8*)&ldsA[buf][0];
    const bf16x8* Bf = (const bf16x8*)&ldsB[buf][0];
    bf16x8 av[4], bv[4];
    #pragma unroll
    for (int mi = 0; mi < 4; ++mi) av[mi] = Af[(wm * 64 + mi * 16 + rl) * 4 + kb];
    #pragma unroll
    for (int ni = 0; ni < 4; ++ni) bv[ni] = Bf[(wn * 64 + ni * 16 + rl) * 4 + kb];
    #pragma unroll
    for (int mi = 0; mi < 4; ++mi)
      #pragma unroll
      for (int ni = 0; ni < 4; ++ni)
        acc[mi][ni] = __builtin_amdgcn_mfma_f32_16x16x32_bf16(av[mi], bv[ni], acc[mi][ni], 0, 0, 0);
    __syncthreads();
  }

  const int rb = kb * 4;
  #pragma unroll
  for (int mi = 0; mi < 4; ++mi)
    #pragma unroll
    for (int ni = 0; ni < 4; ++ni) {
      size_t rrow = (size_t)(m0 + wm * 64 + mi * 16 + rb);
      size_t col = (size_t)(n0 + wn * 64 + ni * 16 + rl);
      #pragma unroll
      for (int j = 0; j < 4; ++j)
        C[(rrow + j) * (size_t)V_ + col] = acc[mi][ni][j];
    }

  // ---- per-tile row max / sum-exp partials ----
  float tm[4][4];
  #pragma unroll
  for (int mi = 0; mi < 4; ++mi)
    #pragma unroll
    for (int j = 0; j < 4; ++j) {
      float m = fmaxf(fmaxf(acc[mi][0][j], acc[mi][1][j]), fmaxf(acc[mi][2][j], acc[mi][3][j]));
      m = fmaxf(m, __shfl_xor(m, 1)); m = fmaxf(m, __shfl_xor(m, 2));
      m = fmaxf(m, __shfl_xor(m, 4)); m = fmaxf(m, __shfl_xor(m, 8));
      tm[mi][j] = m;
    }
  if (rl == 0) {
    #pragma unroll
    for (int mi = 0; mi < 4; ++mi)
      #pragma unroll
      for (int j = 0; j < 4; ++j)
        smax[wn][wm * 64 + mi * 16 + kb * 4 + j] = tm[mi][j];
  }
  __syncthreads();
  float ts[4][4];
  #pragma unroll
  for (int mi = 0; mi < 4; ++mi)
    #pragma unroll
    for (int j = 0; j < 4; ++j) {
      int rlocal = wm * 64 + mi * 16 + kb * 4 + j;
      float M = fmaxf(smax[0][rlocal], smax[1][rlocal]);
      float s = __expf(acc[mi][0][j] - M) + __expf(acc[mi][1][j] - M) +
                __expf(acc[mi][2][j] - M) + __expf(acc[mi][3][j] - M);
      s += __shfl_xor(s, 1); s += __shfl_xor(s, 2);
      s += __shfl_xor(s, 4); s += __shfl_xor(s, 8);
      ts[mi][j] = s;
    }
  if (rl == 0) {
    #pragma unroll
    for (int mi = 0; mi < 4; ++mi)
      #pragma unroll
      for (int j = 0; j < 4; ++j)
        ssum[wn][wm * 64 + mi * 16 + kb * 4 + j] = ts[mi][j];
  }
  __syncthreads();
  if (tid < 128) {
    float M = fmaxf(smax[0][tid], smax[1][tid]);
    float S = ssum[0][tid] + ssum[1][tid];
    pmax[(size_t)(m0 + tid) * 256 + blockIdx.x] = M;
    psum[(size_t)(m0 + tid) * 256 + blockIdx.x] = S;
  }
}

// ---------------- finish: lse from partials, then C[row] -= lse
__global__ __launch_bounds__(256) void softmax_finish_kernel(
    float* __restrict__ C, const float* __restrict__ pmax, const float* __restrict__ psum) {
  const size_t row = blockIdx.x;
  const int tid = threadIdx.x, lane = tid & 63, wid = tid >> 6;
  __shared__ float red[4];

  float pm = (tid < 250) ? pmax[row * 256 + tid] : -INFINITY;
  float ps = (tid < 250) ? psum[row * 256 + tid] : 0.f;

  float m = pm;
  #pragma unroll
  for (int off = 32; off > 0; off >>= 1) m = fmaxf(m, __shfl_xor(m, off));
  if (lane == 0) red[wid] = m;
  __syncthreads();
  m = fmaxf(fmaxf(red[0], red[1]), fmaxf(red[2], red[3]));
  __syncthreads();

  float s = (tid < 250) ? ps * __expf(pm - m) : 0.f;
  #pragma unroll
  for (int off = 32; off > 0; off >>= 1) s += __shfl_xor(s, off);
  if (lane == 0) red[wid] = s;
  __syncthreads();
  s = red[0] + red[1] + red[2] + red[3];
  const float lse = m + logf(s);

  float4* p4 = (float4*)(C + row * (size_t)V_);
  for (int i = tid; i < 8000; i += 256) {
    float4 v = p4[i];
    v.x -= lse; v.y -= lse; v.z -= lse; v.w -= lse;
    p4[i] = v;
  }
}

extern "C" void kernel_launch(void* const* d_in, const int* in_sizes, int n_in,
                              void* d_out, int out_size, void* d_ws, size_t ws_size,
                              hipStream_t stream) {
  const int*   dst  = (const int*)d_in[0];
  const float* E    = (const float*)d_in[1];
  const float* Wih  = (const float*)d_in[2];
  const float* Whh  = (const float*)d_in[3];
  const float* bih  = (const float*)d_in[4];
  const float* bhh  = (const float*)d_in[5];
  const float* h0   = (const float*)d_in[6];
  const float* c0   = (const float*)d_in[7];
  const float* out0 = (const float*)d_in[8];
  float* C = (float*)d_out;

  char* ws = (char*)d_ws;
  unsigned short* Ebf   = (unsigned short*)(ws);                      // 31.25 MB
  unsigned short* preA2 = (unsigned short*)(ws + (size_t)33554432);   // 16.78 MB
  unsigned short* Wrs   = (unsigned short*)(ws + (size_t)50331648);   // 2.10 MB
  unsigned short* embbf = (unsigned short*)(ws + (size_t)52428800);   // 4.19 MB (pre-phase)
  float*          pmax  = (float*)(ws + (size_t)52428800);            // 4.19 MB (post-phase)
  unsigned short* W1bf  = (unsigned short*)(ws + (size_t)56623104);   // 2.10 MB (pre-phase)
  float*          psum  = (float*)(ws + (size_t)56623104);            // 4.19 MB (post-phase)
  unsigned short* Abf   = (unsigned short*)(ws + (size_t)60817408);   // 4.19 MB
  unsigned short* hb0   = (unsigned short*)(ws + (size_t)65011712);   // 32 KB
  unsigned short* hb1   = (unsigned short*)(ws + (size_t)65044480);   // 32 KB
  float*          cbuf  = (float*)(ws + (size_t)65077248);            // 64 KB

  // --- precompute ---
  embed_bf_kernel<<<dim3(T_ * B_), dim3(64), 0, stream>>>(dst, E, embbf);
  cvt_kernel<<<dim3(2048), dim3(256), 0, stream>>>(E, Ebf, V_ * D_ / 4);
  cvt_w1_kernel<<<dim3(256), dim3(256), 0, stream>>>(Wih, W1bf, 2048 * 512 / 4);
  wr_prep_swz_kernel<<<dim3(256), dim3(256), 0, stream>>>(Wih, Whh, Wrs, 2048 * 512 / 4);

  gemm_pre_kernel<<<dim3(2048 / 128, 4096 / 128), dim3(256), 0, stream>>>(embbf, W1bf, bih, bhh, preA2);
  delta0_kernel<<<dim3(2048), dim3(256), 0, stream>>>(Wih, out0, h0, preA2);

  cvt_kernel<<<dim3(16), dim3(256), 0, stream>>>(h0, hb0, B_ * H_ / 4);
  hipMemcpyAsync(cbuf, c0, (size_t)B_ * H_ * 4, hipMemcpyDeviceToDevice, stream);

  // --- recurrence ---
  for (int t = 0; t < T_; ++t) {
    const unsigned short* hin = (t & 1) ? hb1 : hb0;
    unsigned short*       hout = (t & 1) ? hb0 : hb1;
    lstm_step3_kernel<<<dim3(64), dim3(256), 0, stream>>>(
        t, Wrs, preA2, hin, hout, cbuf, Abf);
  }

  // --- projection + fused softmax ---
  gemm_kernel<<<dim3(V_ / 128, (B_ * T_) / 128), dim3(256), 0, stream>>>(Abf, Ebf, C, pmax, psum);
  softmax_finish_kernel<<<dim3(B_ * T_), dim3(256), 0, stream>>>(C, pmax, psum);
}